// Round 12
// baseline (707.059 us; speedup 1.0000x reference)
//
#include <hip/hip_runtime.h>
#include <hip/hip_bf16.h>
#include <cstdint>

// MHGAT: 2-layer multi-head GAT + linear skip, fp32 in/out.
// N=10000 nodes, E=160000 edges, H=4 heads.
// Dense GEMMs: bf16x3 split MFMA, attn+skip pair FUSED per layer (shared A).
// Aggregation: alpha precompute + feature-tiled SpMM, float4 lanes, saddr
// loads, 8-deep gather pipeline (R10: 4-deep left VALU 41% / HBM 48% -> latency).

__device__ __forceinline__ float lrelu(float v) { return v >= 0.f ? v : 0.2f * v; }

// bf16 bit helpers (RNE)
__device__ __forceinline__ short f2bf(float x) {
  unsigned u = __float_as_uint(x);
  unsigned r = (u + 0x7fffu + ((u >> 16) & 1u)) >> 16;
  return (short)r;
}
__device__ __forceinline__ float bf2f(short b) {
  return __uint_as_float(((unsigned)(unsigned short)b) << 16);
}

typedef __attribute__((ext_vector_type(8))) short bf16x8;
typedef __attribute__((ext_vector_type(4))) float f32x4;

__device__ __forceinline__ void gload_lds16(const void* g, void* l) {
  auto gp = (const __attribute__((address_space(1))) unsigned int*)(uintptr_t)g;
  auto lp = (__attribute__((address_space(3))) unsigned int*)(uintptr_t)l;
  __builtin_amdgcn_global_load_lds(gp, lp, 16, 0, 0);
}

// ---------------- CSR build (group edges by destination) ----------------
__global__ void count_edges_k(const int* __restrict__ dstv, int* __restrict__ counts, int E) {
  int e = blockIdx.x * 256 + threadIdx.x;
  if (e < E) atomicAdd(&counts[dstv[e]], 1);
}

__global__ void scan_k(const int* __restrict__ counts, int* __restrict__ rowptr,
                       int* __restrict__ cursor, int n) {
  __shared__ int wsum[16];
  __shared__ int s_base;
  int tid = threadIdx.x, lane = tid & 63, wv = tid >> 6;
  if (tid == 0) s_base = 0;
  __syncthreads();
  for (int base = 0; base < n; base += 1024) {
    int i = base + tid;
    int v = (i < n) ? counts[i] : 0;
    int x = v;
#pragma unroll
    for (int off = 1; off < 64; off <<= 1) {
      int t = __shfl_up(x, off);
      if (lane >= off) x += t;
    }
    if (lane == 63) wsum[wv] = x;
    __syncthreads();
    int woff = 0, tot = 0;
#pragma unroll
    for (int w = 0; w < 16; ++w) {
      int s = wsum[w];
      tot += s;
      if (w < wv) woff += s;
    }
    int b = s_base;
    if (i < n) {
      int excl = b + woff + x - v;
      rowptr[i] = excl;
      cursor[i] = excl;
    }
    __syncthreads();
    if (tid == 0) s_base = b + tot;
  }
  __syncthreads();
  if (tid == 0) rowptr[n] = s_base;
}

__global__ void fill_csr_k(const int* __restrict__ srcv, const int* __restrict__ dstv,
                           int* __restrict__ cursor, int* __restrict__ csr_src, int E) {
  int e = blockIdx.x * 256 + threadIdx.x;
  if (e < E) {
    int p = atomicAdd(&cursor[dstv[e]], 1);
    csr_src[p] = srcv[e];
  }
}

// ---------------- input split: x[N,300] -> xh/xl [N,320] bf16, zero-pad ----------------
__global__ void xsplit_k(const float* __restrict__ x, short* __restrict__ xh,
                         short* __restrict__ xl, int total) {  // total = N*320
  int idx = blockIdx.x * 256 + threadIdx.x;
  if (idx >= total) return;
  int n = idx / 320, k = idx - n * 320;
  float v = (k < 300) ? x[(size_t)n * 300 + k] : 0.f;
  short h = f2bf(v);
  xh[idx] = h;
  xl[idx] = f2bf(v - bf2f(h));
}

// ---------------- weight transpose + split: W[Kin,Nn] -> Wt{h,l}[Nn,Kpad] ----------------
__global__ void wsplit_t_k(const float* __restrict__ W, short* __restrict__ Wth,
                           short* __restrict__ Wtl, int Nn, int Kin, int Kpad) {
  int idx = blockIdx.x * 256 + threadIdx.x;
  if (idx >= Nn * Kpad) return;
  int n = idx / Kpad, k = idx - n * Kpad;
  float a = (k < Kin) ? W[(size_t)k * Nn + n] : 0.f;
  short h = f2bf(a);
  Wth[idx] = h;
  Wtl[idx] = f2bf(a - bf2f(h));
}

// ---------------- fused bf16x3 split-MFMA GEMM pair: {C1,C2} = A@[B1;B2] ----------------
// Ah/Al [M,K] row-major; Bh/Bl transposed [2*NS,K] (rows 0..NS-1 = B1 out-cols,
// NS.. = B2 out-cols). Output col gc < NS -> C1[.,gc]; else C2[.,gc-NS] + bias2.
// Both C row stride = NS. 128x128 tile, 4 waves, BK=32, global_load_lds staging.
__global__ __launch_bounds__(256) void gemm_bf16x3_k(
    const short* __restrict__ Ah, const short* __restrict__ Al,
    const short* __restrict__ Bh, const short* __restrict__ Bl,
    const float* __restrict__ bias2, float* __restrict__ C1, float* __restrict__ C2,
    int M, int NS, int K) {
  __shared__ __align__(16) short Ash[128 * 32];
  __shared__ __align__(16) short Asl[128 * 32];
  __shared__ __align__(16) short Bsh[128 * 32];
  __shared__ __align__(16) short Bsl[128 * 32];
  int tid = threadIdx.x, w = tid >> 6, l = tid & 63;
  int m0 = blockIdx.y * 128, n0 = blockIdx.x * 128;
  int wm = (w >> 1) * 64, wn = (w & 1) * 64;

  f32x4 acc[4][4] = {};

  int r_in = l >> 2;
  int kq = (l & 3) * 8;
  int arow_base = m0 + w * 32 + r_in;
  int brow_base = n0 + w * 32 + r_in;
  int lbase = (w * 32) * 32;

  int fr = l & 15, fk = (l >> 4) * 8;

  for (int k0 = 0; k0 < K; k0 += 32) {
    __syncthreads();
#pragma unroll
    for (int i = 0; i < 2; ++i) {
      int am = min(arow_base + i * 16, M - 1);
      int bn = brow_base + i * 16;
      size_t aoff = (size_t)am * K + k0 + kq;
      size_t boff = (size_t)bn * K + k0 + kq;
      int lofs = lbase + i * (16 * 32);
      gload_lds16(Ah + aoff, &Ash[lofs]);
      gload_lds16(Al + aoff, &Asl[lofs]);
      gload_lds16(Bh + boff, &Bsh[lofs]);
      gload_lds16(Bl + boff, &Bsl[lofs]);
    }
    __syncthreads();

    bf16x8 afh[4], afl[4], bfh[4], bfl[4];
#pragma unroll
    for (int t = 0; t < 4; ++t) {
      int ar = wm + t * 16 + fr;
      afh[t] = *(const bf16x8*)&Ash[ar * 32 + fk];
      afl[t] = *(const bf16x8*)&Asl[ar * 32 + fk];
      int br = wn + t * 16 + fr;
      bfh[t] = *(const bf16x8*)&Bsh[br * 32 + fk];
      bfl[t] = *(const bf16x8*)&Bsl[br * 32 + fk];
    }
#pragma unroll
    for (int mi = 0; mi < 4; ++mi)
#pragma unroll
      for (int ni = 0; ni < 4; ++ni) {
        acc[mi][ni] = __builtin_amdgcn_mfma_f32_16x16x32_bf16(afh[mi], bfh[ni], acc[mi][ni], 0, 0, 0);
        acc[mi][ni] = __builtin_amdgcn_mfma_f32_16x16x32_bf16(afh[mi], bfl[ni], acc[mi][ni], 0, 0, 0);
        acc[mi][ni] = __builtin_amdgcn_mfma_f32_16x16x32_bf16(afl[mi], bfh[ni], acc[mi][ni], 0, 0, 0);
      }
  }

  // C/D layout (m89/m91): col = lane&15, row = (lane>>4)*4 + reg
  int fq = (l >> 4) * 4;
#pragma unroll
  for (int ni = 0; ni < 4; ++ni) {
    int gc = n0 + wn + ni * 16 + fr;
    bool second = gc >= NS;
    float bv = second ? bias2[gc - NS] : 0.f;
    float* Cp = second ? C2 : C1;
    int cc = second ? gc - NS : gc;
#pragma unroll
    for (int mi = 0; mi < 4; ++mi) {
      int grb = m0 + wm + mi * 16 + fq;
#pragma unroll
      for (int r = 0; r < 4; ++r) {
        int gr = grb + r;
        if (gr < M) Cp[(size_t)gr * NS + cc] = acc[mi][ni][r] + bv;
      }
    }
  }
}

// ---------------- attention coefficients: al_s/al_d [N,H] ----------------
template <int C>
__global__ __launch_bounds__(256) void att_coef_k(
    const float* __restrict__ hfeat, const float* __restrict__ a_src,
    const float* __restrict__ a_dst, float* __restrict__ al_s,
    float* __restrict__ al_d, int n) {
  int wave = threadIdx.x >> 6, lane = threadIdx.x & 63;
  int node = blockIdx.x * 4 + wave;
  if (node >= n) return;
  constexpr int F = 4 * C;
  const float* hrow = hfeat + (size_t)node * F;
  float s[4] = {0, 0, 0, 0}, d[4] = {0, 0, 0, 0};
  for (int f = lane; f < F; f += 64) {
    float hv = hrow[f];
    int h = f / C;
    s[h] = fmaf(hv, a_src[f], s[h]);
    d[h] = fmaf(hv, a_dst[f], d[h]);
  }
#pragma unroll
  for (int off = 32; off; off >>= 1) {
#pragma unroll
    for (int h = 0; h < 4; ++h) {
      s[h] += __shfl_xor(s[h], off);
      d[h] += __shfl_xor(d[h], off);
    }
  }
  if (lane == 0) {
#pragma unroll
    for (int h = 0; h < 4; ++h) {
      al_s[node * 4 + h] = s[h];
      al_d[node * 4 + h] = d[h];
    }
  }
}

// ---------------- edge softmax weights: alpha[e][h] (CSR position indexed) ----------------
__global__ __launch_bounds__(256) void edge_alpha_k(
    const float* __restrict__ al_s, const float* __restrict__ al_d,
    const int* __restrict__ rowptr, const int* __restrict__ csr_src,
    float* __restrict__ alpha, int N) {
  int wave = threadIdx.x >> 6, lane = threadIdx.x & 63;
  int n = blockIdx.x * 4 + wave;
  if (n >= N) return;
  int r0 = rowptr[n], r1 = rowptr[n + 1];
  float ald[4];
#pragma unroll
  for (int h = 0; h < 4; ++h) ald[h] = al_d[n * 4 + h];

  float m[4] = {-3.4e38f, -3.4e38f, -3.4e38f, -3.4e38f};
  for (int e = r0 + lane; e < r1; e += 64) {
    int s = csr_src[e];
#pragma unroll
    for (int h = 0; h < 4; ++h) m[h] = fmaxf(m[h], lrelu(al_s[s * 4 + h] + ald[h]));
  }
#pragma unroll
  for (int off = 32; off; off >>= 1)
#pragma unroll
    for (int h = 0; h < 4; ++h) m[h] = fmaxf(m[h], __shfl_xor(m[h], off));

  float den[4] = {0, 0, 0, 0};
  for (int e = r0 + lane; e < r1; e += 64) {
    int s = csr_src[e];
#pragma unroll
    for (int h = 0; h < 4; ++h) den[h] += expf(lrelu(al_s[s * 4 + h] + ald[h]) - m[h]);
  }
#pragma unroll
  for (int off = 32; off; off >>= 1)
#pragma unroll
    for (int h = 0; h < 4; ++h) den[h] += __shfl_xor(den[h], off);

  float rden[4];
#pragma unroll
  for (int h = 0; h < 4; ++h) rden[h] = 1.f / fmaxf(den[h], 1e-16f);

  for (int e = r0 + lane; e < r1; e += 64) {
    int s = csr_src[e];
#pragma unroll
    for (int h = 0; h < 4; ++h)
      alpha[(size_t)e * 4 + h] = expf(lrelu(al_s[s * 4 + h] + ald[h]) - m[h]) * rden[h];
  }
}

// ---------------- feature-tiled SpMM: vector tiles, saddr loads, 8-deep pipeline ----------------
template <int F, int TILE, bool RELU, bool SPLIT>
__global__ __launch_bounds__(256) void spmm_k(
    const float* __restrict__ hfeat, const float* __restrict__ alpha,
    const int* __restrict__ rowptr, const int* __restrict__ csr_src,
    const float* __restrict__ bias, const float* __restrict__ skip,
    float* __restrict__ out, short* __restrict__ oh, short* __restrict__ ol, int N) {
  constexpr int VE = TILE / 64;        // floats per lane
  constexpr int C = F / 4;             // head dim
  int wave = threadIdx.x >> 6, lane = threadIdx.x & 63;
  int n = blockIdx.x * 4 + wave;
  if (n >= N) return;
  int y = blockIdx.y;
  int col = y * TILE + lane * VE;
  int head = (y * TILE) / C;           // uniform per block (TILE <= C)
  int r0 = rowptr[n], r1 = rowptr[n + 1];
  int len = r1 - r0;
  unsigned laneoff = (unsigned)(lane * VE);

  float acc[8][VE] = {};
  for (int base = 0; base < len; base += 64) {
    unsigned sj = 0;
    float aj = 0.f;
    if (base + lane < len) {
      int e = r0 + base + lane;
      sj = (unsigned)csr_src[e] * (unsigned)F + (unsigned)(y * TILE);
      aj = alpha[(size_t)e * 4 + head];
    }
    int cnt = min(64, len - base);
    int j = 0;
    for (; j + 8 <= cnt; j += 8) {
#pragma unroll
      for (int q = 0; q < 8; ++q) {
        unsigned sF = (unsigned)__builtin_amdgcn_readlane((int)sj, j + q);  // uniform
        float a = __uint_as_float(
            (unsigned)__builtin_amdgcn_readlane((int)__float_as_uint(aj), j + q));
        const float* row = hfeat + sF;  // SGPR base -> saddr-form load
        if (VE == 4) {
          float4 v = *(const float4*)(row + laneoff);
          acc[q][0] = fmaf(a, v.x, acc[q][0]);
          acc[q][1] = fmaf(a, v.y, acc[q][1]);
          acc[q][2] = fmaf(a, v.z, acc[q][2]);
          acc[q][3] = fmaf(a, v.w, acc[q][3]);
        } else {
          float2 v = *(const float2*)(row + laneoff);
          acc[q][0] = fmaf(a, v.x, acc[q][0]);
          acc[q][1] = fmaf(a, v.y, acc[q][1]);
        }
      }
    }
    for (; j < cnt; ++j) {
      unsigned sF = (unsigned)__builtin_amdgcn_readlane((int)sj, j);
      float a = __uint_as_float(
          (unsigned)__builtin_amdgcn_readlane((int)__float_as_uint(aj), j));
      const float* row = hfeat + sF;
      if (VE == 4) {
        float4 v = *(const float4*)(row + laneoff);
        acc[j & 7][0] = fmaf(a, v.x, acc[j & 7][0]);
        acc[j & 7][1] = fmaf(a, v.y, acc[j & 7][1]);
        acc[j & 7][2] = fmaf(a, v.z, acc[j & 7][2]);
        acc[j & 7][3] = fmaf(a, v.w, acc[j & 7][3]);
      } else {
        float2 v = *(const float2*)(row + laneoff);
        acc[j & 7][0] = fmaf(a, v.x, acc[j & 7][0]);
        acc[j & 7][1] = fmaf(a, v.y, acc[j & 7][1]);
      }
    }
  }

  size_t o = (size_t)n * F + col;
  float r[VE];
#pragma unroll
  for (int v = 0; v < VE; ++v)
    r[v] = (((acc[0][v] + acc[1][v]) + (acc[2][v] + acc[3][v])) +
            ((acc[4][v] + acc[5][v]) + (acc[6][v] + acc[7][v]))) +
           bias[col + v] + skip[o + v];
  if (RELU) {
#pragma unroll
    for (int v = 0; v < VE; ++v) r[v] = fmaxf(r[v], 0.f);
  }
  if (SPLIT) {
#pragma unroll
    for (int v = 0; v < VE; ++v) {
      short h = f2bf(r[v]);
      oh[o + v] = h;
      ol[o + v] = f2bf(r[v] - bf2f(h));
    }
  } else {
#pragma unroll
    for (int v = 0; v < VE; ++v) out[o + v] = r[v];
  }
}

extern "C" void kernel_launch(void* const* d_in, const int* in_sizes, int n_in,
                              void* d_out, int out_size, void* d_ws, size_t ws_size,
                              hipStream_t stream) {
  (void)n_in; (void)out_size; (void)ws_size;
  const float* x   = (const float*)d_in[0];
  const int*   ei  = (const int*)d_in[1];
  const float* W1  = (const float*)d_in[2];
  const float* as1 = (const float*)d_in[3];
  const float* ad1 = (const float*)d_in[4];
  const float* b1  = (const float*)d_in[5];
  const float* Wl1 = (const float*)d_in[6];
  const float* bl1 = (const float*)d_in[7];
  const float* W2  = (const float*)d_in[8];
  const float* as2 = (const float*)d_in[9];
  const float* ad2 = (const float*)d_in[10];
  const float* b2  = (const float*)d_in[11];
  const float* Wl2 = (const float*)d_in[12];
  const float* bl2 = (const float*)d_in[13];

  const int N = 10000;
  const int E = in_sizes[1] / 2;
  const int* srcv = ei;
  const int* dstv = ei + E;

  // ---- workspace layout (~122 MB) ----
  char* p = (char*)d_ws;
  float* hfeat = (float*)p; p += (size_t)N * 2048 * 4;  // 80 MB, multi-era
  float* s1 = hfeat + (size_t)N * 512;
  short* xh = (short*)(hfeat + (size_t)N * 1024);
  short* xl = xh + (size_t)N * 320;
  short* h1h = (short*)p; p += (size_t)N * 512 * 2;
  short* h1l = (short*)p; p += (size_t)N * 512 * 2;
  short* w2cat_h = (short*)p; p += (size_t)4096 * 512 * 2;  // [W2t; Wl2t]
  short* w2cat_l = (short*)p; p += (size_t)4096 * 512 * 2;
  short* w1cat_h = (short*)p; p += (size_t)1024 * 320 * 2;  // [W1t; Wl1t]
  short* w1cat_l = (short*)p; p += (size_t)1024 * 320 * 2;
  float* als = (float*)p; p += (size_t)N * 4 * 4;
  float* ald = (float*)p; p += (size_t)N * 4 * 4;
  float* alpha = (float*)p; p += (size_t)E * 4 * 4;
  int* rowptr = (int*)p; p += (N + 1) * 4;
  int* cursor = (int*)p; p += N * 4;
  int* counts = (int*)p; p += N * 4;
  int* csr_src = (int*)p; p += (size_t)E * 4;

  // ---- CSR build ----
  hipMemsetAsync(counts, 0, N * sizeof(int), stream);
  count_edges_k<<<(E + 255) / 256, 256, 0, stream>>>(dstv, counts, E);
  scan_k<<<1, 1024, 0, stream>>>(counts, rowptr, cursor, N);
  fill_csr_k<<<(E + 255) / 256, 256, 0, stream>>>(srcv, dstv, cursor, csr_src, E);

  // ---- splits (weights concatenated: rows [0,NS)=attn W, [NS,2NS)=skip W) ----
  xsplit_k<<<(N * 320 + 255) / 256, 256, 0, stream>>>(x, xh, xl, N * 320);
  wsplit_t_k<<<(512 * 320 + 255) / 256, 256, 0, stream>>>(W1, w1cat_h, w1cat_l, 512, 300, 320);
  wsplit_t_k<<<(512 * 320 + 255) / 256, 256, 0, stream>>>(
      Wl1, w1cat_h + (size_t)512 * 320, w1cat_l + (size_t)512 * 320, 512, 300, 320);
  wsplit_t_k<<<(2048 * 512 + 255) / 256, 256, 0, stream>>>(W2, w2cat_h, w2cat_l, 2048, 512, 512);
  wsplit_t_k<<<(2048 * 512 + 255) / 256, 256, 0, stream>>>(
      Wl2, w2cat_h + (size_t)2048 * 512, w2cat_l + (size_t)2048 * 512, 2048, 512, 512);

  // ---- Layer 1: fused GEMM pair (x @ [W1|Wl1]) -> hfeat, s1(+bl1); relu after agg ----
  gemm_bf16x3_k<<<dim3(1024 / 128, (N + 127) / 128), 256, 0, stream>>>(
      xh, xl, w1cat_h, w1cat_l, bl1, hfeat, s1, N, 512, 320);
  att_coef_k<128><<<(N + 3) / 4, 256, 0, stream>>>(hfeat, as1, ad1, als, ald, N);
  edge_alpha_k<<<(N + 3) / 4, 256, 0, stream>>>(als, ald, rowptr, csr_src, alpha, N);
  spmm_k<512, 128, true, true><<<dim3((N + 3) / 4, 512 / 128), 256, 0, stream>>>(
      hfeat, alpha, rowptr, csr_src, b1, s1, nullptr, h1h, h1l, N);

  // ---- Layer 2: fused GEMM pair (h1 @ [W2|Wl2]) -> hfeat, d_out(+bl2) ----
  gemm_bf16x3_k<<<dim3(4096 / 128, (N + 127) / 128), 256, 0, stream>>>(
      h1h, h1l, w2cat_h, w2cat_l, bl2, hfeat, (float*)d_out, N, 2048, 512);
  att_coef_k<512><<<(N + 3) / 4, 256, 0, stream>>>(hfeat, as2, ad2, als, ald, N);
  edge_alpha_k<<<(N + 3) / 4, 256, 0, stream>>>(als, ald, rowptr, csr_src, alpha, N);
  spmm_k<2048, 256, false, false><<<dim3((N + 3) / 4, 2048 / 256), 256, 0, stream>>>(
      hfeat, alpha, rowptr, csr_src, b2, (float*)d_out, (float*)d_out, nullptr, nullptr, N);
}

// Round 13
// 624.099 us; speedup vs baseline: 1.1329x; 1.1329x over previous
//
#include <hip/hip_runtime.h>
#include <hip/hip_bf16.h>
#include <cstdint>

// MHGAT: 2-layer multi-head GAT + linear skip, fp32 in/out.
// N=10000 nodes, E=160000 edges, H=4 heads.
// Dense GEMMs: bf16x3 split MFMA, attn+skip pair FUSED per layer (shared A).
// Aggregation: alpha precompute + feature-tiled SpMM, float4 lanes, saddr
// loads, 4-deep gather pipeline. (R12 post-mortem: 8-deep blew VGPR budget ->
// occupancy 51%, loads serialized, 250us; 4-deep measured 155us in R10.)

__device__ __forceinline__ float lrelu(float v) { return v >= 0.f ? v : 0.2f * v; }

// bf16 bit helpers (RNE)
__device__ __forceinline__ short f2bf(float x) {
  unsigned u = __float_as_uint(x);
  unsigned r = (u + 0x7fffu + ((u >> 16) & 1u)) >> 16;
  return (short)r;
}
__device__ __forceinline__ float bf2f(short b) {
  return __uint_as_float(((unsigned)(unsigned short)b) << 16);
}

typedef __attribute__((ext_vector_type(8))) short bf16x8;
typedef __attribute__((ext_vector_type(4))) float f32x4;

__device__ __forceinline__ void gload_lds16(const void* g, void* l) {
  auto gp = (const __attribute__((address_space(1))) unsigned int*)(uintptr_t)g;
  auto lp = (__attribute__((address_space(3))) unsigned int*)(uintptr_t)l;
  __builtin_amdgcn_global_load_lds(gp, lp, 16, 0, 0);
}

// ---------------- CSR build (group edges by destination) ----------------
__global__ void count_edges_k(const int* __restrict__ dstv, int* __restrict__ counts, int E) {
  int e = blockIdx.x * 256 + threadIdx.x;
  if (e < E) atomicAdd(&counts[dstv[e]], 1);
}

__global__ void scan_k(const int* __restrict__ counts, int* __restrict__ rowptr,
                       int* __restrict__ cursor, int n) {
  __shared__ int wsum[16];
  __shared__ int s_base;
  int tid = threadIdx.x, lane = tid & 63, wv = tid >> 6;
  if (tid == 0) s_base = 0;
  __syncthreads();
  for (int base = 0; base < n; base += 1024) {
    int i = base + tid;
    int v = (i < n) ? counts[i] : 0;
    int x = v;
#pragma unroll
    for (int off = 1; off < 64; off <<= 1) {
      int t = __shfl_up(x, off);
      if (lane >= off) x += t;
    }
    if (lane == 63) wsum[wv] = x;
    __syncthreads();
    int woff = 0, tot = 0;
#pragma unroll
    for (int w = 0; w < 16; ++w) {
      int s = wsum[w];
      tot += s;
      if (w < wv) woff += s;
    }
    int b = s_base;
    if (i < n) {
      int excl = b + woff + x - v;
      rowptr[i] = excl;
      cursor[i] = excl;
    }
    __syncthreads();
    if (tid == 0) s_base = b + tot;
  }
  __syncthreads();
  if (tid == 0) rowptr[n] = s_base;
}

__global__ void fill_csr_k(const int* __restrict__ srcv, const int* __restrict__ dstv,
                           int* __restrict__ cursor, int* __restrict__ csr_src, int E) {
  int e = blockIdx.x * 256 + threadIdx.x;
  if (e < E) {
    int p = atomicAdd(&cursor[dstv[e]], 1);
    csr_src[p] = srcv[e];
  }
}

// ---------------- input split: x[N,300] -> xh/xl [N,320] bf16, zero-pad ----------------
__global__ void xsplit_k(const float* __restrict__ x, short* __restrict__ xh,
                         short* __restrict__ xl, int total) {  // total = N*320
  int idx = blockIdx.x * 256 + threadIdx.x;
  if (idx >= total) return;
  int n = idx / 320, k = idx - n * 320;
  float v = (k < 300) ? x[(size_t)n * 300 + k] : 0.f;
  short h = f2bf(v);
  xh[idx] = h;
  xl[idx] = f2bf(v - bf2f(h));
}

// ---------------- weight transpose + split: W[Kin,Nn] -> Wt{h,l}[Nn,Kpad] ----------------
__global__ void wsplit_t_k(const float* __restrict__ W, short* __restrict__ Wth,
                           short* __restrict__ Wtl, int Nn, int Kin, int Kpad) {
  int idx = blockIdx.x * 256 + threadIdx.x;
  if (idx >= Nn * Kpad) return;
  int n = idx / Kpad, k = idx - n * Kpad;
  float a = (k < Kin) ? W[(size_t)k * Nn + n] : 0.f;
  short h = f2bf(a);
  Wth[idx] = h;
  Wtl[idx] = f2bf(a - bf2f(h));
}

// ---------------- fused bf16x3 split-MFMA GEMM pair: {C1,C2} = A@[B1;B2] ----------------
// Ah/Al [M,K] row-major; Bh/Bl transposed [2*NS,K] (rows 0..NS-1 = B1 out-cols,
// NS.. = B2 out-cols). Output col gc < NS -> C1[.,gc]; else C2[.,gc-NS] + bias2.
// Both C row stride = NS. 128x128 tile, 4 waves, BK=32, global_load_lds staging.
__global__ __launch_bounds__(256) void gemm_bf16x3_k(
    const short* __restrict__ Ah, const short* __restrict__ Al,
    const short* __restrict__ Bh, const short* __restrict__ Bl,
    const float* __restrict__ bias2, float* __restrict__ C1, float* __restrict__ C2,
    int M, int NS, int K) {
  __shared__ __align__(16) short Ash[128 * 32];
  __shared__ __align__(16) short Asl[128 * 32];
  __shared__ __align__(16) short Bsh[128 * 32];
  __shared__ __align__(16) short Bsl[128 * 32];
  int tid = threadIdx.x, w = tid >> 6, l = tid & 63;
  int m0 = blockIdx.y * 128, n0 = blockIdx.x * 128;
  int wm = (w >> 1) * 64, wn = (w & 1) * 64;

  f32x4 acc[4][4] = {};

  int r_in = l >> 2;
  int kq = (l & 3) * 8;
  int arow_base = m0 + w * 32 + r_in;
  int brow_base = n0 + w * 32 + r_in;
  int lbase = (w * 32) * 32;

  int fr = l & 15, fk = (l >> 4) * 8;

  for (int k0 = 0; k0 < K; k0 += 32) {
    __syncthreads();
#pragma unroll
    for (int i = 0; i < 2; ++i) {
      int am = min(arow_base + i * 16, M - 1);
      int bn = brow_base + i * 16;
      size_t aoff = (size_t)am * K + k0 + kq;
      size_t boff = (size_t)bn * K + k0 + kq;
      int lofs = lbase + i * (16 * 32);
      gload_lds16(Ah + aoff, &Ash[lofs]);
      gload_lds16(Al + aoff, &Asl[lofs]);
      gload_lds16(Bh + boff, &Bsh[lofs]);
      gload_lds16(Bl + boff, &Bsl[lofs]);
    }
    __syncthreads();

    bf16x8 afh[4], afl[4], bfh[4], bfl[4];
#pragma unroll
    for (int t = 0; t < 4; ++t) {
      int ar = wm + t * 16 + fr;
      afh[t] = *(const bf16x8*)&Ash[ar * 32 + fk];
      afl[t] = *(const bf16x8*)&Asl[ar * 32 + fk];
      int br = wn + t * 16 + fr;
      bfh[t] = *(const bf16x8*)&Bsh[br * 32 + fk];
      bfl[t] = *(const bf16x8*)&Bsl[br * 32 + fk];
    }
#pragma unroll
    for (int mi = 0; mi < 4; ++mi)
#pragma unroll
      for (int ni = 0; ni < 4; ++ni) {
        acc[mi][ni] = __builtin_amdgcn_mfma_f32_16x16x32_bf16(afh[mi], bfh[ni], acc[mi][ni], 0, 0, 0);
        acc[mi][ni] = __builtin_amdgcn_mfma_f32_16x16x32_bf16(afh[mi], bfl[ni], acc[mi][ni], 0, 0, 0);
        acc[mi][ni] = __builtin_amdgcn_mfma_f32_16x16x32_bf16(afl[mi], bfh[ni], acc[mi][ni], 0, 0, 0);
      }
  }

  // C/D layout (m89/m91): col = lane&15, row = (lane>>4)*4 + reg
  int fq = (l >> 4) * 4;
#pragma unroll
  for (int ni = 0; ni < 4; ++ni) {
    int gc = n0 + wn + ni * 16 + fr;
    bool second = gc >= NS;
    float bv = second ? bias2[gc - NS] : 0.f;
    float* Cp = second ? C2 : C1;
    int cc = second ? gc - NS : gc;
#pragma unroll
    for (int mi = 0; mi < 4; ++mi) {
      int grb = m0 + wm + mi * 16 + fq;
#pragma unroll
      for (int r = 0; r < 4; ++r) {
        int gr = grb + r;
        if (gr < M) Cp[(size_t)gr * NS + cc] = acc[mi][ni][r] + bv;
      }
    }
  }
}

// ---------------- attention coefficients: al_s/al_d [N,H] ----------------
template <int C>
__global__ __launch_bounds__(256) void att_coef_k(
    const float* __restrict__ hfeat, const float* __restrict__ a_src,
    const float* __restrict__ a_dst, float* __restrict__ al_s,
    float* __restrict__ al_d, int n) {
  int wave = threadIdx.x >> 6, lane = threadIdx.x & 63;
  int node = blockIdx.x * 4 + wave;
  if (node >= n) return;
  constexpr int F = 4 * C;
  const float* hrow = hfeat + (size_t)node * F;
  float s[4] = {0, 0, 0, 0}, d[4] = {0, 0, 0, 0};
  for (int f = lane; f < F; f += 64) {
    float hv = hrow[f];
    int h = f / C;
    s[h] = fmaf(hv, a_src[f], s[h]);
    d[h] = fmaf(hv, a_dst[f], d[h]);
  }
#pragma unroll
  for (int off = 32; off; off >>= 1) {
#pragma unroll
    for (int h = 0; h < 4; ++h) {
      s[h] += __shfl_xor(s[h], off);
      d[h] += __shfl_xor(d[h], off);
    }
  }
  if (lane == 0) {
#pragma unroll
    for (int h = 0; h < 4; ++h) {
      al_s[node * 4 + h] = s[h];
      al_d[node * 4 + h] = d[h];
    }
  }
}

// ---------------- edge softmax weights: alpha[e][h] (CSR position indexed) ----------------
__global__ __launch_bounds__(256) void edge_alpha_k(
    const float* __restrict__ al_s, const float* __restrict__ al_d,
    const int* __restrict__ rowptr, const int* __restrict__ csr_src,
    float* __restrict__ alpha, int N) {
  int wave = threadIdx.x >> 6, lane = threadIdx.x & 63;
  int n = blockIdx.x * 4 + wave;
  if (n >= N) return;
  int r0 = rowptr[n], r1 = rowptr[n + 1];
  float ald[4];
#pragma unroll
  for (int h = 0; h < 4; ++h) ald[h] = al_d[n * 4 + h];

  float m[4] = {-3.4e38f, -3.4e38f, -3.4e38f, -3.4e38f};
  for (int e = r0 + lane; e < r1; e += 64) {
    int s = csr_src[e];
#pragma unroll
    for (int h = 0; h < 4; ++h) m[h] = fmaxf(m[h], lrelu(al_s[s * 4 + h] + ald[h]));
  }
#pragma unroll
  for (int off = 32; off; off >>= 1)
#pragma unroll
    for (int h = 0; h < 4; ++h) m[h] = fmaxf(m[h], __shfl_xor(m[h], off));

  float den[4] = {0, 0, 0, 0};
  for (int e = r0 + lane; e < r1; e += 64) {
    int s = csr_src[e];
#pragma unroll
    for (int h = 0; h < 4; ++h) den[h] += expf(lrelu(al_s[s * 4 + h] + ald[h]) - m[h]);
  }
#pragma unroll
  for (int off = 32; off; off >>= 1)
#pragma unroll
    for (int h = 0; h < 4; ++h) den[h] += __shfl_xor(den[h], off);

  float rden[4];
#pragma unroll
  for (int h = 0; h < 4; ++h) rden[h] = 1.f / fmaxf(den[h], 1e-16f);

  for (int e = r0 + lane; e < r1; e += 64) {
    int s = csr_src[e];
#pragma unroll
    for (int h = 0; h < 4; ++h)
      alpha[(size_t)e * 4 + h] = expf(lrelu(al_s[s * 4 + h] + ald[h]) - m[h]) * rden[h];
  }
}

// ---------------- feature-tiled SpMM: vector tiles, saddr loads, 4-deep pipeline ----------------
template <int F, int TILE, bool RELU, bool SPLIT>
__global__ __launch_bounds__(256) void spmm_k(
    const float* __restrict__ hfeat, const float* __restrict__ alpha,
    const int* __restrict__ rowptr, const int* __restrict__ csr_src,
    const float* __restrict__ bias, const float* __restrict__ skip,
    float* __restrict__ out, short* __restrict__ oh, short* __restrict__ ol, int N) {
  constexpr int VE = TILE / 64;        // floats per lane
  constexpr int C = F / 4;             // head dim
  int wave = threadIdx.x >> 6, lane = threadIdx.x & 63;
  int n = blockIdx.x * 4 + wave;
  if (n >= N) return;
  int y = blockIdx.y;
  int col = y * TILE + lane * VE;
  int head = (y * TILE) / C;           // uniform per block (TILE <= C)
  int r0 = rowptr[n], r1 = rowptr[n + 1];
  int len = r1 - r0;
  unsigned laneoff = (unsigned)(lane * VE);

  float acc[4][VE] = {};
  for (int base = 0; base < len; base += 64) {
    // lane-parallel preload; fold tile base into the row offset
    unsigned sj = 0;
    float aj = 0.f;
    if (base + lane < len) {
      int e = r0 + base + lane;
      sj = (unsigned)csr_src[e] * (unsigned)F + (unsigned)(y * TILE);
      aj = alpha[(size_t)e * 4 + head];
    }
    int cnt = min(64, len - base);
    int j = 0;
    for (; j + 4 <= cnt; j += 4) {
#pragma unroll
      for (int q = 0; q < 4; ++q) {
        unsigned sF = (unsigned)__builtin_amdgcn_readlane((int)sj, j + q);  // uniform
        float a = __uint_as_float(
            (unsigned)__builtin_amdgcn_readlane((int)__float_as_uint(aj), j + q));
        const float* row = hfeat + sF;  // SGPR base -> saddr-form load
        if (VE == 4) {
          float4 v = *(const float4*)(row + laneoff);
          acc[q][0] = fmaf(a, v.x, acc[q][0]);
          acc[q][1] = fmaf(a, v.y, acc[q][1]);
          acc[q][2] = fmaf(a, v.z, acc[q][2]);
          acc[q][3] = fmaf(a, v.w, acc[q][3]);
        } else {
          float2 v = *(const float2*)(row + laneoff);
          acc[q][0] = fmaf(a, v.x, acc[q][0]);
          acc[q][1] = fmaf(a, v.y, acc[q][1]);
        }
      }
    }
    for (; j < cnt; ++j) {
      unsigned sF = (unsigned)__builtin_amdgcn_readlane((int)sj, j);
      float a = __uint_as_float(
          (unsigned)__builtin_amdgcn_readlane((int)__float_as_uint(aj), j));
      const float* row = hfeat + sF;
      if (VE == 4) {
        float4 v = *(const float4*)(row + laneoff);
        acc[j & 3][0] = fmaf(a, v.x, acc[j & 3][0]);
        acc[j & 3][1] = fmaf(a, v.y, acc[j & 3][1]);
        acc[j & 3][2] = fmaf(a, v.z, acc[j & 3][2]);
        acc[j & 3][3] = fmaf(a, v.w, acc[j & 3][3]);
      } else {
        float2 v = *(const float2*)(row + laneoff);
        acc[j & 3][0] = fmaf(a, v.x, acc[j & 3][0]);
        acc[j & 3][1] = fmaf(a, v.y, acc[j & 3][1]);
      }
    }
  }

  // epilogue: combine 4 acc sets, + bias + skip, optional relu, store
  size_t o = (size_t)n * F + col;
  float r[VE];
#pragma unroll
  for (int v = 0; v < VE; ++v)
    r[v] = ((acc[0][v] + acc[1][v]) + (acc[2][v] + acc[3][v])) +
           bias[col + v] + skip[o + v];
  if (RELU) {
#pragma unroll
    for (int v = 0; v < VE; ++v) r[v] = fmaxf(r[v], 0.f);
  }
  if (SPLIT) {
#pragma unroll
    for (int v = 0; v < VE; ++v) {
      short h = f2bf(r[v]);
      oh[o + v] = h;
      ol[o + v] = f2bf(r[v] - bf2f(h));
    }
  } else {
#pragma unroll
    for (int v = 0; v < VE; ++v) out[o + v] = r[v];
  }
}

extern "C" void kernel_launch(void* const* d_in, const int* in_sizes, int n_in,
                              void* d_out, int out_size, void* d_ws, size_t ws_size,
                              hipStream_t stream) {
  (void)n_in; (void)out_size; (void)ws_size;
  const float* x   = (const float*)d_in[0];
  const int*   ei  = (const int*)d_in[1];
  const float* W1  = (const float*)d_in[2];
  const float* as1 = (const float*)d_in[3];
  const float* ad1 = (const float*)d_in[4];
  const float* b1  = (const float*)d_in[5];
  const float* Wl1 = (const float*)d_in[6];
  const float* bl1 = (const float*)d_in[7];
  const float* W2  = (const float*)d_in[8];
  const float* as2 = (const float*)d_in[9];
  const float* ad2 = (const float*)d_in[10];
  const float* b2  = (const float*)d_in[11];
  const float* Wl2 = (const float*)d_in[12];
  const float* bl2 = (const float*)d_in[13];

  const int N = 10000;
  const int E = in_sizes[1] / 2;
  const int* srcv = ei;
  const int* dstv = ei + E;

  // ---- workspace layout (~122 MB) ----
  char* p = (char*)d_ws;
  float* hfeat = (float*)p; p += (size_t)N * 2048 * 4;  // 80 MB, multi-era
  float* s1 = hfeat + (size_t)N * 512;
  short* xh = (short*)(hfeat + (size_t)N * 1024);
  short* xl = xh + (size_t)N * 320;
  short* h1h = (short*)p; p += (size_t)N * 512 * 2;
  short* h1l = (short*)p; p += (size_t)N * 512 * 2;
  short* w2cat_h = (short*)p; p += (size_t)4096 * 512 * 2;  // [W2t; Wl2t]
  short* w2cat_l = (short*)p; p += (size_t)4096 * 512 * 2;
  short* w1cat_h = (short*)p; p += (size_t)1024 * 320 * 2;  // [W1t; Wl1t]
  short* w1cat_l = (short*)p; p += (size_t)1024 * 320 * 2;
  float* als = (float*)p; p += (size_t)N * 4 * 4;
  float* ald = (float*)p; p += (size_t)N * 4 * 4;
  float* alpha = (float*)p; p += (size_t)E * 4 * 4;
  int* rowptr = (int*)p; p += (N + 1) * 4;
  int* cursor = (int*)p; p += N * 4;
  int* counts = (int*)p; p += N * 4;
  int* csr_src = (int*)p; p += (size_t)E * 4;

  // ---- CSR build ----
  hipMemsetAsync(counts, 0, N * sizeof(int), stream);
  count_edges_k<<<(E + 255) / 256, 256, 0, stream>>>(dstv, counts, E);
  scan_k<<<1, 1024, 0, stream>>>(counts, rowptr, cursor, N);
  fill_csr_k<<<(E + 255) / 256, 256, 0, stream>>>(srcv, dstv, cursor, csr_src, E);

  // ---- splits (weights concatenated: rows [0,NS)=attn W, [NS,2NS)=skip W) ----
  xsplit_k<<<(N * 320 + 255) / 256, 256, 0, stream>>>(x, xh, xl, N * 320);
  wsplit_t_k<<<(512 * 320 + 255) / 256, 256, 0, stream>>>(W1, w1cat_h, w1cat_l, 512, 300, 320);
  wsplit_t_k<<<(512 * 320 + 255) / 256, 256, 0, stream>>>(
      Wl1, w1cat_h + (size_t)512 * 320, w1cat_l + (size_t)512 * 320, 512, 300, 320);
  wsplit_t_k<<<(2048 * 512 + 255) / 256, 256, 0, stream>>>(W2, w2cat_h, w2cat_l, 2048, 512, 512);
  wsplit_t_k<<<(2048 * 512 + 255) / 256, 256, 0, stream>>>(
      Wl2, w2cat_h + (size_t)2048 * 512, w2cat_l + (size_t)2048 * 512, 2048, 512, 512);

  // ---- Layer 1: fused GEMM pair (x @ [W1|Wl1]) -> hfeat, s1(+bl1); relu after agg ----
  gemm_bf16x3_k<<<dim3(1024 / 128, (N + 127) / 128), 256, 0, stream>>>(
      xh, xl, w1cat_h, w1cat_l, bl1, hfeat, s1, N, 512, 320);
  att_coef_k<128><<<(N + 3) / 4, 256, 0, stream>>>(hfeat, as1, ad1, als, ald, N);
  edge_alpha_k<<<(N + 3) / 4, 256, 0, stream>>>(als, ald, rowptr, csr_src, alpha, N);
  spmm_k<512, 128, true, true><<<dim3((N + 3) / 4, 512 / 128), 256, 0, stream>>>(
      hfeat, alpha, rowptr, csr_src, b1, s1, nullptr, h1h, h1l, N);

  // ---- Layer 2: fused GEMM pair (h1 @ [W2|Wl2]) -> hfeat, d_out(+bl2) ----
  gemm_bf16x3_k<<<dim3(4096 / 128, (N + 127) / 128), 256, 0, stream>>>(
      h1h, h1l, w2cat_h, w2cat_l, bl2, hfeat, (float*)d_out, N, 2048, 512);
  att_coef_k<512><<<(N + 3) / 4, 256, 0, stream>>>(hfeat, as2, ad2, als, ald, N);
  edge_alpha_k<<<(N + 3) / 4, 256, 0, stream>>>(als, ald, rowptr, csr_src, alpha, N);
  spmm_k<2048, 256, false, false><<<dim3((N + 3) / 4, 2048 / 256), 256, 0, stream>>>(
      hfeat, alpha, rowptr, csr_src, b2, (float*)d_out, (float*)d_out, nullptr, nullptr, N);
}

// Round 14
// 619.285 us; speedup vs baseline: 1.1417x; 1.0078x over previous
//
#include <hip/hip_runtime.h>
#include <hip/hip_bf16.h>
#include <cstdint>

// MHGAT: 2-layer multi-head GAT + linear skip, fp32 in/out.
// N=10000 nodes, E=160000 edges, H=4 heads.
// Dense GEMMs: bf16x3 split MFMA, attn+skip pair fused per layer (shared A),
// LDS k-slot XOR swizzle (R13: 1e7 bank-conflict cycles from 8-way ds_read;
// swizzle via pre-swizzled global source + swizzled read, rule #21).
// Aggregation: alpha precompute + feature-tiled SpMM, float4 lanes, saddr
// loads, 4-deep gather pipeline (8-deep regressed: VGPR/occupancy, R12).

__device__ __forceinline__ float lrelu(float v) { return v >= 0.f ? v : 0.2f * v; }

// bf16 bit helpers (RNE)
__device__ __forceinline__ short f2bf(float x) {
  unsigned u = __float_as_uint(x);
  unsigned r = (u + 0x7fffu + ((u >> 16) & 1u)) >> 16;
  return (short)r;
}
__device__ __forceinline__ float bf2f(short b) {
  return __uint_as_float(((unsigned)(unsigned short)b) << 16);
}

typedef __attribute__((ext_vector_type(8))) short bf16x8;
typedef __attribute__((ext_vector_type(4))) float f32x4;

__device__ __forceinline__ void gload_lds16(const void* g, void* l) {
  auto gp = (const __attribute__((address_space(1))) unsigned int*)(uintptr_t)g;
  auto lp = (__attribute__((address_space(3))) unsigned int*)(uintptr_t)l;
  __builtin_amdgcn_global_load_lds(gp, lp, 16, 0, 0);
}

// ---------------- CSR build (group edges by destination) ----------------
__global__ void count_edges_k(const int* __restrict__ dstv, int* __restrict__ counts, int E) {
  int e = blockIdx.x * 256 + threadIdx.x;
  if (e < E) atomicAdd(&counts[dstv[e]], 1);
}

__global__ void scan_k(const int* __restrict__ counts, int* __restrict__ rowptr,
                       int* __restrict__ cursor, int n) {
  __shared__ int wsum[16];
  __shared__ int s_base;
  int tid = threadIdx.x, lane = tid & 63, wv = tid >> 6;
  if (tid == 0) s_base = 0;
  __syncthreads();
  for (int base = 0; base < n; base += 1024) {
    int i = base + tid;
    int v = (i < n) ? counts[i] : 0;
    int x = v;
#pragma unroll
    for (int off = 1; off < 64; off <<= 1) {
      int t = __shfl_up(x, off);
      if (lane >= off) x += t;
    }
    if (lane == 63) wsum[wv] = x;
    __syncthreads();
    int woff = 0, tot = 0;
#pragma unroll
    for (int w = 0; w < 16; ++w) {
      int s = wsum[w];
      tot += s;
      if (w < wv) woff += s;
    }
    int b = s_base;
    if (i < n) {
      int excl = b + woff + x - v;
      rowptr[i] = excl;
      cursor[i] = excl;
    }
    __syncthreads();
    if (tid == 0) s_base = b + tot;
  }
  __syncthreads();
  if (tid == 0) rowptr[n] = s_base;
}

__global__ void fill_csr_k(const int* __restrict__ srcv, const int* __restrict__ dstv,
                           int* __restrict__ cursor, int* __restrict__ csr_src, int E) {
  int e = blockIdx.x * 256 + threadIdx.x;
  if (e < E) {
    int p = atomicAdd(&cursor[dstv[e]], 1);
    csr_src[p] = srcv[e];
  }
}

// ---------------- input split: x[N,300] -> xh/xl [N,320] bf16, zero-pad ----------------
__global__ void xsplit_k(const float* __restrict__ x, short* __restrict__ xh,
                         short* __restrict__ xl, int total) {  // total = N*320
  int idx = blockIdx.x * 256 + threadIdx.x;
  if (idx >= total) return;
  int n = idx / 320, k = idx - n * 320;
  float v = (k < 300) ? x[(size_t)n * 300 + k] : 0.f;
  short h = f2bf(v);
  xh[idx] = h;
  xl[idx] = f2bf(v - bf2f(h));
}

// ---------------- weight transpose + split: W[Kin,Nn] -> Wt{h,l}[Nn,Kpad] ----------------
__global__ void wsplit_t_k(const float* __restrict__ W, short* __restrict__ Wth,
                           short* __restrict__ Wtl, int Nn, int Kin, int Kpad) {
  int idx = blockIdx.x * 256 + threadIdx.x;
  if (idx >= Nn * Kpad) return;
  int n = idx / Kpad, k = idx - n * Kpad;
  float a = (k < Kin) ? W[(size_t)k * Nn + n] : 0.f;
  short h = f2bf(a);
  Wth[idx] = h;
  Wtl[idx] = f2bf(a - bf2f(h));
}

// ---------------- fused bf16x3 split-MFMA GEMM pair: {C1,C2} = A@[B1;B2] ----------------
// Ah/Al [M,K] row-major; Bh/Bl transposed [2*NS,K]. Col gc < NS -> C1; else
// C2[.,gc-NS] + bias2. 128x128 tile, 4 waves, BK=32, global_load_lds staging.
// LDS k-slot swizzle: LDS[row][s] holds global[row][s ^ ((row>>2)&3)]
// (swizzle carried by the per-lane GLOBAL source; LDS writes stay linear, m104).
// Read at slot g^(fr>>2) returns global slot g; start banks spread 2->8 per
// 16-lane group => 8-way conflict -> 2-way (free, m136).
__global__ __launch_bounds__(256) void gemm_bf16x3_k(
    const short* __restrict__ Ah, const short* __restrict__ Al,
    const short* __restrict__ Bh, const short* __restrict__ Bl,
    const float* __restrict__ bias2, float* __restrict__ C1, float* __restrict__ C2,
    int M, int NS, int K) {
  __shared__ __align__(16) short Ash[128 * 32];
  __shared__ __align__(16) short Asl[128 * 32];
  __shared__ __align__(16) short Bsh[128 * 32];
  __shared__ __align__(16) short Bsl[128 * 32];
  int tid = threadIdx.x, w = tid >> 6, l = tid & 63;
  int m0 = blockIdx.y * 128, n0 = blockIdx.x * 128;
  int wm = (w >> 1) * 64, wn = (w & 1) * 64;

  f32x4 acc[4][4] = {};

  int r_in = l >> 2;
  // swizzled source k-slot: (l&3) ^ ((row>>2)&3), row = w*32+i*16+(l>>2) -> (l>>4)&3
  int kq = (((l & 3) ^ ((l >> 4) & 3))) * 8;
  int arow_base = m0 + w * 32 + r_in;
  int brow_base = n0 + w * 32 + r_in;
  int lbase = (w * 32) * 32;

  int fr = l & 15, g = l >> 4;
  int slot = (g ^ (fr >> 2)) * 8;  // swizzled read slot (row>>2&3 == fr>>2 for all t)

  for (int k0 = 0; k0 < K; k0 += 32) {
    __syncthreads();
#pragma unroll
    for (int i = 0; i < 2; ++i) {
      int am = min(arow_base + i * 16, M - 1);
      int bn = brow_base + i * 16;
      size_t aoff = (size_t)am * K + k0 + kq;
      size_t boff = (size_t)bn * K + k0 + kq;
      int lofs = lbase + i * (16 * 32);
      gload_lds16(Ah + aoff, &Ash[lofs]);
      gload_lds16(Al + aoff, &Asl[lofs]);
      gload_lds16(Bh + boff, &Bsh[lofs]);
      gload_lds16(Bl + boff, &Bsl[lofs]);
    }
    __syncthreads();

    bf16x8 afh[4], afl[4], bfh[4], bfl[4];
#pragma unroll
    for (int t = 0; t < 4; ++t) {
      int ar = wm + t * 16 + fr;
      afh[t] = *(const bf16x8*)&Ash[ar * 32 + slot];
      afl[t] = *(const bf16x8*)&Asl[ar * 32 + slot];
      int br = wn + t * 16 + fr;
      bfh[t] = *(const bf16x8*)&Bsh[br * 32 + slot];
      bfl[t] = *(const bf16x8*)&Bsl[br * 32 + slot];
    }
#pragma unroll
    for (int mi = 0; mi < 4; ++mi)
#pragma unroll
      for (int ni = 0; ni < 4; ++ni) {
        acc[mi][ni] = __builtin_amdgcn_mfma_f32_16x16x32_bf16(afh[mi], bfh[ni], acc[mi][ni], 0, 0, 0);
        acc[mi][ni] = __builtin_amdgcn_mfma_f32_16x16x32_bf16(afh[mi], bfl[ni], acc[mi][ni], 0, 0, 0);
        acc[mi][ni] = __builtin_amdgcn_mfma_f32_16x16x32_bf16(afl[mi], bfh[ni], acc[mi][ni], 0, 0, 0);
      }
  }

  // C/D layout (m89/m91): col = lane&15, row = (lane>>4)*4 + reg
  int fq = (l >> 4) * 4;
#pragma unroll
  for (int ni = 0; ni < 4; ++ni) {
    int gc = n0 + wn + ni * 16 + fr;
    bool second = gc >= NS;
    float bv = second ? bias2[gc - NS] : 0.f;
    float* Cp = second ? C2 : C1;
    int cc = second ? gc - NS : gc;
#pragma unroll
    for (int mi = 0; mi < 4; ++mi) {
      int grb = m0 + wm + mi * 16 + fq;
#pragma unroll
      for (int r = 0; r < 4; ++r) {
        int gr = grb + r;
        if (gr < M) Cp[(size_t)gr * NS + cc] = acc[mi][ni][r] + bv;
      }
    }
  }
}

// ---------------- attention coefficients: al_s/al_d [N,H] ----------------
template <int C>
__global__ __launch_bounds__(256) void att_coef_k(
    const float* __restrict__ hfeat, const float* __restrict__ a_src,
    const float* __restrict__ a_dst, float* __restrict__ al_s,
    float* __restrict__ al_d, int n) {
  int wave = threadIdx.x >> 6, lane = threadIdx.x & 63;
  int node = blockIdx.x * 4 + wave;
  if (node >= n) return;
  constexpr int F = 4 * C;
  const float* hrow = hfeat + (size_t)node * F;
  float s[4] = {0, 0, 0, 0}, d[4] = {0, 0, 0, 0};
  for (int f = lane; f < F; f += 64) {
    float hv = hrow[f];
    int h = f / C;
    s[h] = fmaf(hv, a_src[f], s[h]);
    d[h] = fmaf(hv, a_dst[f], d[h]);
  }
#pragma unroll
  for (int off = 32; off; off >>= 1) {
#pragma unroll
    for (int h = 0; h < 4; ++h) {
      s[h] += __shfl_xor(s[h], off);
      d[h] += __shfl_xor(d[h], off);
    }
  }
  if (lane == 0) {
#pragma unroll
    for (int h = 0; h < 4; ++h) {
      al_s[node * 4 + h] = s[h];
      al_d[node * 4 + h] = d[h];
    }
  }
}

// ---------------- edge softmax weights: alpha[e][h] (CSR position indexed) ----------------
__global__ __launch_bounds__(256) void edge_alpha_k(
    const float* __restrict__ al_s, const float* __restrict__ al_d,
    const int* __restrict__ rowptr, const int* __restrict__ csr_src,
    float* __restrict__ alpha, int N) {
  int wave = threadIdx.x >> 6, lane = threadIdx.x & 63;
  int n = blockIdx.x * 4 + wave;
  if (n >= N) return;
  int r0 = rowptr[n], r1 = rowptr[n + 1];
  float ald[4];
#pragma unroll
  for (int h = 0; h < 4; ++h) ald[h] = al_d[n * 4 + h];

  float m[4] = {-3.4e38f, -3.4e38f, -3.4e38f, -3.4e38f};
  for (int e = r0 + lane; e < r1; e += 64) {
    int s = csr_src[e];
#pragma unroll
    for (int h = 0; h < 4; ++h) m[h] = fmaxf(m[h], lrelu(al_s[s * 4 + h] + ald[h]));
  }
#pragma unroll
  for (int off = 32; off; off >>= 1)
#pragma unroll
    for (int h = 0; h < 4; ++h) m[h] = fmaxf(m[h], __shfl_xor(m[h], off));

  float den[4] = {0, 0, 0, 0};
  for (int e = r0 + lane; e < r1; e += 64) {
    int s = csr_src[e];
#pragma unroll
    for (int h = 0; h < 4; ++h) den[h] += expf(lrelu(al_s[s * 4 + h] + ald[h]) - m[h]);
  }
#pragma unroll
  for (int off = 32; off; off >>= 1)
#pragma unroll
    for (int h = 0; h < 4; ++h) den[h] += __shfl_xor(den[h], off);

  float rden[4];
#pragma unroll
  for (int h = 0; h < 4; ++h) rden[h] = 1.f / fmaxf(den[h], 1e-16f);

  for (int e = r0 + lane; e < r1; e += 64) {
    int s = csr_src[e];
#pragma unroll
    for (int h = 0; h < 4; ++h)
      alpha[(size_t)e * 4 + h] = expf(lrelu(al_s[s * 4 + h] + ald[h]) - m[h]) * rden[h];
  }
}

// ---------------- feature-tiled SpMM: vector tiles, saddr loads, 4-deep pipeline ----------------
template <int F, int TILE, bool RELU, bool SPLIT>
__global__ __launch_bounds__(256) void spmm_k(
    const float* __restrict__ hfeat, const float* __restrict__ alpha,
    const int* __restrict__ rowptr, const int* __restrict__ csr_src,
    const float* __restrict__ bias, const float* __restrict__ skip,
    float* __restrict__ out, short* __restrict__ oh, short* __restrict__ ol, int N) {
  constexpr int VE = TILE / 64;        // floats per lane
  constexpr int C = F / 4;             // head dim
  int wave = threadIdx.x >> 6, lane = threadIdx.x & 63;
  int n = blockIdx.x * 4 + wave;
  if (n >= N) return;
  int y = blockIdx.y;
  int col = y * TILE + lane * VE;
  int head = (y * TILE) / C;           // uniform per block (TILE <= C)
  int r0 = rowptr[n], r1 = rowptr[n + 1];
  int len = r1 - r0;
  unsigned laneoff = (unsigned)(lane * VE);

  float acc[4][VE] = {};
  for (int base = 0; base < len; base += 64) {
    // lane-parallel preload; fold tile base into the row offset
    unsigned sj = 0;
    float aj = 0.f;
    if (base + lane < len) {
      int e = r0 + base + lane;
      sj = (unsigned)csr_src[e] * (unsigned)F + (unsigned)(y * TILE);
      aj = alpha[(size_t)e * 4 + head];
    }
    int cnt = min(64, len - base);
    int j = 0;
    for (; j + 4 <= cnt; j += 4) {
#pragma unroll
      for (int q = 0; q < 4; ++q) {
        unsigned sF = (unsigned)__builtin_amdgcn_readlane((int)sj, j + q);  // uniform
        float a = __uint_as_float(
            (unsigned)__builtin_amdgcn_readlane((int)__float_as_uint(aj), j + q));
        const float* row = hfeat + sF;  // SGPR base -> saddr-form load
        if (VE == 4) {
          float4 v = *(const float4*)(row + laneoff);
          acc[q][0] = fmaf(a, v.x, acc[q][0]);
          acc[q][1] = fmaf(a, v.y, acc[q][1]);
          acc[q][2] = fmaf(a, v.z, acc[q][2]);
          acc[q][3] = fmaf(a, v.w, acc[q][3]);
        } else {
          float2 v = *(const float2*)(row + laneoff);
          acc[q][0] = fmaf(a, v.x, acc[q][0]);
          acc[q][1] = fmaf(a, v.y, acc[q][1]);
        }
      }
    }
    for (; j < cnt; ++j) {
      unsigned sF = (unsigned)__builtin_amdgcn_readlane((int)sj, j);
      float a = __uint_as_float(
          (unsigned)__builtin_amdgcn_readlane((int)__float_as_uint(aj), j));
      const float* row = hfeat + sF;
      if (VE == 4) {
        float4 v = *(const float4*)(row + laneoff);
        acc[j & 3][0] = fmaf(a, v.x, acc[j & 3][0]);
        acc[j & 3][1] = fmaf(a, v.y, acc[j & 3][1]);
        acc[j & 3][2] = fmaf(a, v.z, acc[j & 3][2]);
        acc[j & 3][3] = fmaf(a, v.w, acc[j & 3][3]);
      } else {
        float2 v = *(const float2*)(row + laneoff);
        acc[j & 3][0] = fmaf(a, v.x, acc[j & 3][0]);
        acc[j & 3][1] = fmaf(a, v.y, acc[j & 3][1]);
      }
    }
  }

  // epilogue: combine 4 acc sets, + bias + skip, optional relu, store
  size_t o = (size_t)n * F + col;
  float r[VE];
#pragma unroll
  for (int v = 0; v < VE; ++v)
    r[v] = ((acc[0][v] + acc[1][v]) + (acc[2][v] + acc[3][v])) +
           bias[col + v] + skip[o + v];
  if (RELU) {
#pragma unroll
    for (int v = 0; v < VE; ++v) r[v] = fmaxf(r[v], 0.f);
  }
  if (SPLIT) {
#pragma unroll
    for (int v = 0; v < VE; ++v) {
      short h = f2bf(r[v]);
      oh[o + v] = h;
      ol[o + v] = f2bf(r[v] - bf2f(h));
    }
  } else {
#pragma unroll
    for (int v = 0; v < VE; ++v) out[o + v] = r[v];
  }
}

extern "C" void kernel_launch(void* const* d_in, const int* in_sizes, int n_in,
                              void* d_out, int out_size, void* d_ws, size_t ws_size,
                              hipStream_t stream) {
  (void)n_in; (void)out_size; (void)ws_size;
  const float* x   = (const float*)d_in[0];
  const int*   ei  = (const int*)d_in[1];
  const float* W1  = (const float*)d_in[2];
  const float* as1 = (const float*)d_in[3];
  const float* ad1 = (const float*)d_in[4];
  const float* b1  = (const float*)d_in[5];
  const float* Wl1 = (const float*)d_in[6];
  const float* bl1 = (const float*)d_in[7];
  const float* W2  = (const float*)d_in[8];
  const float* as2 = (const float*)d_in[9];
  const float* ad2 = (const float*)d_in[10];
  const float* b2  = (const float*)d_in[11];
  const float* Wl2 = (const float*)d_in[12];
  const float* bl2 = (const float*)d_in[13];

  const int N = 10000;
  const int E = in_sizes[1] / 2;
  const int* srcv = ei;
  const int* dstv = ei + E;

  // ---- workspace layout (~122 MB) ----
  char* p = (char*)d_ws;
  float* hfeat = (float*)p; p += (size_t)N * 2048 * 4;  // 80 MB, multi-era
  float* s1 = hfeat + (size_t)N * 512;
  short* xh = (short*)(hfeat + (size_t)N * 1024);
  short* xl = xh + (size_t)N * 320;
  short* h1h = (short*)p; p += (size_t)N * 512 * 2;
  short* h1l = (short*)p; p += (size_t)N * 512 * 2;
  short* w2cat_h = (short*)p; p += (size_t)4096 * 512 * 2;  // [W2t; Wl2t]
  short* w2cat_l = (short*)p; p += (size_t)4096 * 512 * 2;
  short* w1cat_h = (short*)p; p += (size_t)1024 * 320 * 2;  // [W1t; Wl1t]
  short* w1cat_l = (short*)p; p += (size_t)1024 * 320 * 2;
  float* als = (float*)p; p += (size_t)N * 4 * 4;
  float* ald = (float*)p; p += (size_t)N * 4 * 4;
  float* alpha = (float*)p; p += (size_t)E * 4 * 4;
  int* rowptr = (int*)p; p += (N + 1) * 4;
  int* cursor = (int*)p; p += N * 4;
  int* counts = (int*)p; p += N * 4;
  int* csr_src = (int*)p; p += (size_t)E * 4;

  // ---- CSR build ----
  hipMemsetAsync(counts, 0, N * sizeof(int), stream);
  count_edges_k<<<(E + 255) / 256, 256, 0, stream>>>(dstv, counts, E);
  scan_k<<<1, 1024, 0, stream>>>(counts, rowptr, cursor, N);
  fill_csr_k<<<(E + 255) / 256, 256, 0, stream>>>(srcv, dstv, cursor, csr_src, E);

  // ---- splits (weights concatenated: rows [0,NS)=attn W, [NS,2NS)=skip W) ----
  xsplit_k<<<(N * 320 + 255) / 256, 256, 0, stream>>>(x, xh, xl, N * 320);
  wsplit_t_k<<<(512 * 320 + 255) / 256, 256, 0, stream>>>(W1, w1cat_h, w1cat_l, 512, 300, 320);
  wsplit_t_k<<<(512 * 320 + 255) / 256, 256, 0, stream>>>(
      Wl1, w1cat_h + (size_t)512 * 320, w1cat_l + (size_t)512 * 320, 512, 300, 320);
  wsplit_t_k<<<(2048 * 512 + 255) / 256, 256, 0, stream>>>(W2, w2cat_h, w2cat_l, 2048, 512, 512);
  wsplit_t_k<<<(2048 * 512 + 255) / 256, 256, 0, stream>>>(
      Wl2, w2cat_h + (size_t)2048 * 512, w2cat_l + (size_t)2048 * 512, 2048, 512, 512);

  // ---- Layer 1: fused GEMM pair (x @ [W1|Wl1]) -> hfeat, s1(+bl1); relu after agg ----
  gemm_bf16x3_k<<<dim3(1024 / 128, (N + 127) / 128), 256, 0, stream>>>(
      xh, xl, w1cat_h, w1cat_l, bl1, hfeat, s1, N, 512, 320);
  att_coef_k<128><<<(N + 3) / 4, 256, 0, stream>>>(hfeat, as1, ad1, als, ald, N);
  edge_alpha_k<<<(N + 3) / 4, 256, 0, stream>>>(als, ald, rowptr, csr_src, alpha, N);
  spmm_k<512, 128, true, true><<<dim3((N + 3) / 4, 512 / 128), 256, 0, stream>>>(
      hfeat, alpha, rowptr, csr_src, b1, s1, nullptr, h1h, h1l, N);

  // ---- Layer 2: fused GEMM pair (h1 @ [W2|Wl2]) -> hfeat, d_out(+bl2) ----
  gemm_bf16x3_k<<<dim3(4096 / 128, (N + 127) / 128), 256, 0, stream>>>(
      h1h, h1l, w2cat_h, w2cat_l, bl2, hfeat, (float*)d_out, N, 2048, 512);
  att_coef_k<512><<<(N + 3) / 4, 256, 0, stream>>>(hfeat, as2, ad2, als, ald, N);
  edge_alpha_k<<<(N + 3) / 4, 256, 0, stream>>>(als, ald, rowptr, csr_src, alpha, N);
  spmm_k<2048, 256, false, false><<<dim3((N + 3) / 4, 2048 / 256), 256, 0, stream>>>(
      hfeat, alpha, rowptr, csr_src, b2, (float*)d_out, (float*)d_out, nullptr, nullptr, N);
}